// Round 6
// baseline (3224.799 us; speedup 1.0000x reference)
//
#include <hip/hip_runtime.h>
#include <math.h>

#define KTOP 2000
#define MAXOUT 500
#define CANDCAP 4096          // candidate capacity (global buffers)
#define NSEL 3600             // approx-score rank margin for selection
#define RC2 16                // candidates per rescore block (256 groups)

typedef __attribute__((ext_vector_type(8))) short short8;
typedef __attribute__((ext_vector_type(4))) float f32x4;

__device__ __forceinline__ unsigned short f2bf(float f) {
  unsigned int u = __float_as_uint(f);
  unsigned int r = ((u >> 16) & 1u) + 0x7FFFu;
  return (unsigned short)((u + r) >> 16);
}

// ---------------------------------------------------------------------------
// transpose+convert: W[K][N] f32 -> WT[N][K] bf16.  grid (K/32, N/32), 256 thr
// ---------------------------------------------------------------------------
__global__ __launch_bounds__(256) void transpose_bf16_kernel(
    const float* __restrict__ W, unsigned short* __restrict__ WT, int K, int N)
{
  __shared__ float t[32][33];
  const int k0 = blockIdx.x << 5, n0 = blockIdx.y << 5;
  const int tid = threadIdx.x;
  const int r = tid >> 5, c = tid & 31;
#pragma unroll
  for (int p = 0; p < 4; ++p)
    t[r + (p << 3)][c] = W[(size_t)(k0 + r + (p << 3)) * N + n0 + c];
  __syncthreads();
#pragma unroll
  for (int p = 0; p < 4; ++p)
    WT[(size_t)(n0 + r + (p << 3)) * K + k0 + c] = f2bf(t[c][r + (p << 3)]);
}

// ---------------------------------------------------------------------------
// conv1 via bf16 MFMA: 3x3 128->1024 + bias + relu -> x1b (bf16, chunk-local)
// ---------------------------------------------------------------------------
#define LSTR 72   // LDS row stride in bf16 elements (144 B)
__global__ __launch_bounds__(256) void conv1_mfma(
    const float* __restrict__ df, const unsigned short* __restrict__ WcT,
    const float* __restrict__ bc, unsigned short* __restrict__ x1b, int pt0)
{
  __shared__ __align__(16) unsigned short As[128 * LSTR];
  __shared__ __align__(16) unsigned short Bs[128 * LSTR];
  const int tid = threadIdx.x;
  const int n0 = blockIdx.x << 7;
  const int m0 = blockIdx.y << 7;             // chunk-local pixel base
  const int Pbase = (pt0 << 6) + m0;          // global pixel base (mult of 128)
  const int ybase = Pbase >> 8, x0 = Pbase & 255;
  const int wv = tid >> 6, lane = tid & 63;
  const int wm = (wv & 1) << 6, wn = (wv >> 1) << 6;
  const int l15 = lane & 15, quad = lane >> 4;

  f32x4 acc[4][4];
  const f32x4 z4 = {0.f, 0.f, 0.f, 0.f};
#pragma unroll
  for (int i = 0; i < 4; ++i)
#pragma unroll
    for (int j = 0; j < 4; ++j) acc[i][j] = z4;

  for (int kc = 0; kc < 18; ++kc) {
    const int tap = kc >> 1, ci0 = (kc & 1) << 6;
    const int dy = tap / 3 - 1, dx = tap % 3 - 1;
    const int gy = ybase + dy;
    const bool yok = (gy >= 0 && gy < 256);
#pragma unroll
    for (int p = 0; p < 8; ++p) {
      const int r = (p << 4) + (tid >> 4);
      const int c4 = tid & 15;
      const int gx = x0 + r + dx;
      float4 v = make_float4(0.f, 0.f, 0.f, 0.f);
      if (yok && gx >= 0 && gx < 256)
        v = *(const float4*)&df[((size_t)((gy << 8) + gx)) * 128 + ci0 + (c4 << 2)];
      const unsigned int lo = (unsigned int)f2bf(v.x) | ((unsigned int)f2bf(v.y) << 16);
      const unsigned int hi = (unsigned int)f2bf(v.z) | ((unsigned int)f2bf(v.w) << 16);
      *(uint2*)&As[r * LSTR + (c4 << 2)] = make_uint2(lo, hi);
    }
#pragma unroll
    for (int p = 0; p < 4; ++p) {
      const int n = (p << 5) + (tid >> 3);
      const int kg = (tid & 7) << 3;
      const uint4 w = *(const uint4*)&WcT[(size_t)(n0 + n) * 1152 + kc * 64 + kg];
      *(uint4*)&Bs[n * LSTR + kg] = w;
    }
    __syncthreads();
#pragma unroll
    for (int s = 0; s < 2; ++s) {
      short8 a[4], b[4];
#pragma unroll
      for (int i = 0; i < 4; ++i)
        a[i] = *(short8*)&As[(wm + (i << 4) + l15) * LSTR + (s << 5) + (quad << 3)];
#pragma unroll
      for (int i = 0; i < 4; ++i)
        b[i] = *(short8*)&Bs[(wn + (i << 4) + l15) * LSTR + (s << 5) + (quad << 3)];
#pragma unroll
      for (int i = 0; i < 4; ++i)
#pragma unroll
        for (int j = 0; j < 4; ++j)
          acc[i][j] = __builtin_amdgcn_mfma_f32_16x16x32_bf16(a[i], b[j], acc[i][j], 0, 0, 0);
    }
    __syncthreads();
  }
#pragma unroll
  for (int i = 0; i < 4; ++i)
#pragma unroll
    for (int j = 0; j < 4; ++j) {
      const int col = wn + (j << 4) + l15;
      const float bb = bc[n0 + col];
#pragma unroll
      for (int rg = 0; rg < 4; ++rg) {
        const int row = wm + (i << 4) + (quad << 2) + rg;
        const float v = fmaxf(acc[i][j][rg] + bb, 0.f);
        x1b[(size_t)(m0 + row) * 1024 + n0 + col] = f2bf(v);
      }
    }
}

// ---------------------------------------------------------------------------
// fc via bf16 MFMA: 1x1 1024->1024 + bias + relu, fused score partials.
// ---------------------------------------------------------------------------
__global__ __launch_bounds__(256) void fc_mfma(
    const unsigned short* __restrict__ x1b, const unsigned short* __restrict__ WfcT,
    const float* __restrict__ bfc, const float* __restrict__ Wsc,
    float* __restrict__ part, int pt0)
{
  __shared__ __align__(16) unsigned short As[128 * LSTR];
  __shared__ __align__(16) unsigned short Bs[128 * LSTR];
  const int tid = threadIdx.x;
  const int n0 = blockIdx.x << 7;
  const int m0 = blockIdx.y << 7;
  const int Pbase = (pt0 << 6) + m0;
  const int wv = tid >> 6, lane = tid & 63;
  const int wm = (wv & 1) << 6, wn = (wv >> 1) << 6;
  const int l15 = lane & 15, quad = lane >> 4;

  f32x4 acc[4][4];
  const f32x4 z4 = {0.f, 0.f, 0.f, 0.f};
#pragma unroll
  for (int i = 0; i < 4; ++i)
#pragma unroll
    for (int j = 0; j < 4; ++j) acc[i][j] = z4;

  for (int kc = 0; kc < 16; ++kc) {
#pragma unroll
    for (int p = 0; p < 4; ++p) {
      const int r = (p << 5) + (tid >> 3);
      const int kg = (tid & 7) << 3;
      const uint4 w = *(const uint4*)&x1b[(size_t)(m0 + r) * 1024 + kc * 64 + kg];
      *(uint4*)&As[r * LSTR + kg] = w;
    }
#pragma unroll
    for (int p = 0; p < 4; ++p) {
      const int n = (p << 5) + (tid >> 3);
      const int kg = (tid & 7) << 3;
      const uint4 w = *(const uint4*)&WfcT[(size_t)(n0 + n) * 1024 + kc * 64 + kg];
      *(uint4*)&Bs[n * LSTR + kg] = w;
    }
    __syncthreads();
#pragma unroll
    for (int s = 0; s < 2; ++s) {
      short8 a[4], b[4];
#pragma unroll
      for (int i = 0; i < 4; ++i)
        a[i] = *(short8*)&As[(wm + (i << 4) + l15) * LSTR + (s << 5) + (quad << 3)];
#pragma unroll
      for (int i = 0; i < 4; ++i)
        b[i] = *(short8*)&Bs[(wn + (i << 4) + l15) * LSTR + (s << 5) + (quad << 3)];
#pragma unroll
      for (int i = 0; i < 4; ++i)
#pragma unroll
        for (int j = 0; j < 4; ++j)
          acc[i][j] = __builtin_amdgcn_mfma_f32_16x16x32_bf16(a[i], b[j], acc[i][j], 0, 0, 0);
    }
    __syncthreads();
  }
  float wsv[4], bfv[4];
#pragma unroll
  for (int j = 0; j < 4; ++j) {
    const int col = n0 + wn + (j << 4) + l15;
    wsv[j] = Wsc[col];
    bfv[j] = bfc[col];
  }
  float* red = (float*)As;
#pragma unroll
  for (int i = 0; i < 4; ++i)
#pragma unroll
    for (int rg = 0; rg < 4; ++rg) {
      const int row = wm + (i << 4) + (quad << 2) + rg;
      float ps = 0.f;
#pragma unroll
      for (int j = 0; j < 4; ++j) {
        const float v = fmaxf(acc[i][j][rg] + bfv[j], 0.f);
        ps = fmaf(v, wsv[j], ps);
      }
      red[row * 33 + ((wv >> 1) << 4) + l15] = ps;
    }
  __syncthreads();
  if (tid < 128) {
    float s = 0.f;
#pragma unroll
    for (int sl = 0; sl < 32; ++sl) s += red[tid * 33 + sl];
    part[(size_t)blockIdx.x * 65536 + Pbase + tid] = s;
  }
}

// ---------------------------------------------------------------------------
// finalize: sum 8 partials, bias, sigmoid -> f32 approx scores (selection)
// ---------------------------------------------------------------------------
__global__ __launch_bounds__(256) void head_finalize_kernel(
    const float* __restrict__ part, const float* __restrict__ bs,
    float* __restrict__ scores)
{
  const int pix = blockIdx.x * 256 + threadIdx.x;
  float s = 0.f;
#pragma unroll
  for (int cb = 0; cb < 8; ++cb) s += part[(size_t)cb * 65536 + pix];
  s += bs[0];
  scores[pix] = 1.f / (1.f + expf(-s));
}

// ---------------------------------------------------------------------------
// select: radix-select NSEL-th approx score, compact all >= T (rank margin).
// ---------------------------------------------------------------------------
__global__ __launch_bounds__(1024) void select_kernel(
    const float* __restrict__ scores, unsigned int* __restrict__ cand_idx,
    unsigned int* __restrict__ cand_cnt)
{
  __shared__ unsigned int hist[256];
  __shared__ unsigned int sh_prefix;
  const int tid = threadIdx.x;
  if (tid == 0) *cand_cnt = 0u;
  __syncthreads();

  unsigned int prefix = 0u;
  int need = NSEL;
  for (int byte = 3; byte >= 0; --byte) {
    if (tid < 256) hist[tid] = 0u;
    __syncthreads();
    const int sh = byte * 8;
    const unsigned int mhi = (byte == 3) ? 0u : (0xFFFFFFFFu << (sh + 8));
    for (int i = tid; i < 65536; i += 1024) {
      const unsigned int b = __float_as_uint(scores[i]);
      if ((b & mhi) == prefix) atomicAdd(&hist[(b >> sh) & 255u], 1u);
    }
    __syncthreads();
    if (tid == 0) {
      int cum = 0;
      for (int v = 255; v >= 0; --v) {
        const int c = (int)hist[v];
        if (cum + c >= need) { sh_prefix = prefix | ((unsigned)v << sh); break; }
        cum += c;
      }
      hist[0] = (unsigned int)cum;
    }
    __syncthreads();
    prefix = sh_prefix;
    need -= (int)hist[0];
    __syncthreads();
  }
  const float thr = __uint_as_float(prefix);

  for (int i = tid; i < 65536; i += 1024) {
    if (scores[i] >= thr) {
      const unsigned int p = atomicAdd(cand_cnt, 1u);
      if (p < CANDCAP) cand_idx[p] = (unsigned int)i;
    }
  }
  __syncthreads();
  if (tid == 0 && *cand_cnt > CANDCAP) *cand_cnt = CANDCAP;
}

// ---------------------------------------------------------------------------
// rescore_conv: f64 conv1 for RC2 candidates per block -> x1g (global f64).
// Thread owns co = 4*tid+j (float4 weight loads, 1/4 the load instrs).
// 256 groups -> exactly 1 block/CU, weight traffic = groups * 4.7 MB.
// ---------------------------------------------------------------------------
__global__ __launch_bounds__(256) void rescore_conv(
    const float* __restrict__ df, const float* __restrict__ Wc,
    const float* __restrict__ bc,
    const unsigned int* __restrict__ cand_idx,
    const unsigned int* __restrict__ cand_cnt,
    double* __restrict__ x1g)
{
  __shared__ float patt[RC2][132];
  const int cnt = (int)*cand_cnt;
  const int c0 = blockIdx.x * RC2;
  if (c0 >= cnt) return;
  const int tid = threadIdx.x;

  int rr[RC2], cc[RC2];
#pragma unroll
  for (int c = 0; c < RC2; ++c) {
    const int slot = (c0 + c < cnt) ? c0 + c : c0;
    const unsigned int idx = cand_idx[slot];
    rr[c] = (int)(idx >> 8); cc[c] = (int)(idx & 255u);
  }

  double acc[4][RC2];
#pragma unroll
  for (int j = 0; j < 4; ++j)
#pragma unroll
    for (int c = 0; c < RC2; ++c) acc[j][c] = 0.0;

  for (int tap = 0; tap < 9; ++tap) {
    const int dy = tap / 3 - 1, dx = tap % 3 - 1;
    for (int t = tid; t < RC2 * 128; t += 256) {
      const int c = t >> 7, ci = t & 127;
      const int gy = rr[c] + dy, gx = cc[c] + dx;
      float v = 0.f;
      if (gy >= 0 && gy < 256 && gx >= 0 && gx < 256)
        v = df[((size_t)((gy << 8) + gx)) * 128 + ci];
      patt[c][ci] = v;
    }
    __syncthreads();
    const float* wbase = &Wc[(size_t)(tap << 7) * 1024 + (tid << 2)];
    float4 wf = *(const float4*)wbase;
    for (int ci = 0; ci < 128; ++ci) {
      const float4 wfn = (ci + 1 < 128)
          ? *(const float4*)(wbase + (size_t)(ci + 1) * 1024) : wf;
      double w[4];
      w[0] = (double)wf.x; w[1] = (double)wf.y;
      w[2] = (double)wf.z; w[3] = (double)wf.w;
#pragma unroll
      for (int c = 0; c < RC2; ++c) {
        const double p = (double)patt[c][ci];
#pragma unroll
        for (int j = 0; j < 4; ++j) acc[j][c] = fma(w[j], p, acc[j][c]);
      }
      wf = wfn;
    }
    __syncthreads();
  }
  const float4 bf4 = *(const float4*)&bc[tid << 2];
  const double b4[4] = {(double)bf4.x, (double)bf4.y, (double)bf4.z, (double)bf4.w};
#pragma unroll
  for (int c = 0; c < RC2; ++c) {
    if (c0 + c < cnt) {
      double v0 = acc[0][c] + b4[0]; v0 = v0 > 0.0 ? v0 : 0.0;
      double v1 = acc[1][c] + b4[1]; v1 = v1 > 0.0 ? v1 : 0.0;
      double v2 = acc[2][c] + b4[2]; v2 = v2 > 0.0 ? v2 : 0.0;
      double v3 = acc[3][c] + b4[3]; v3 = v3 > 0.0 ? v3 : 0.0;
      double2* o = (double2*)&x1g[(size_t)(c0 + c) * 1024 + (tid << 2)];
      o[0] = make_double2(v0, v1);
      o[1] = make_double2(v2, v3);
    }
  }
}

// ---------------------------------------------------------------------------
// rescore_fc: f64 fc + heads for RC2 candidates per block, x1 from x1g.
// Heads computed per-candidate right after use (keeps VGPR pressure low).
// ---------------------------------------------------------------------------
__global__ __launch_bounds__(256) void rescore_fc(
    const double* __restrict__ x1g, const float* __restrict__ Wfc,
    const float* __restrict__ bfc, const float* __restrict__ Wsc,
    const float* __restrict__ bs, const float* __restrict__ Wrg,
    const float* __restrict__ br,
    const unsigned int* __restrict__ cand_cnt,
    unsigned long long* __restrict__ cand_sb,
    double* __restrict__ cand_ry, double* __restrict__ cand_rx)
{
  __shared__ double xbuf[RC2][264];    // 33.8 KB
  __shared__ double redd[256];
  const int cnt = (int)*cand_cnt;
  const int c0 = blockIdx.x * RC2;
  if (c0 >= cnt) return;
  const int tid = threadIdx.x;

  double a2[4][RC2];
#pragma unroll
  for (int j = 0; j < 4; ++j)
#pragma unroll
    for (int c = 0; c < RC2; ++c) a2[j][c] = 0.0;

  for (int kc = 0; kc < 4; ++kc) {
    __syncthreads();
#pragma unroll
    for (int c = 0; c < RC2; ++c) {
      const int row = (c0 + c < cnt) ? c0 + c : c0;
      xbuf[c][tid] = x1g[(size_t)row * 1024 + (kc << 8) + tid];
    }
    __syncthreads();
    const float* wbase = &Wfc[(size_t)(kc << 8) * 1024 + (tid << 2)];
    float4 wf = *(const float4*)wbase;
    for (int kk = 0; kk < 256; ++kk) {
      const float4 wfn = (kk + 1 < 256)
          ? *(const float4*)(wbase + (size_t)(kk + 1) * 1024) : wf;
      double w[4];
      w[0] = (double)wf.x; w[1] = (double)wf.y;
      w[2] = (double)wf.z; w[3] = (double)wf.w;
#pragma unroll
      for (int c = 0; c < RC2; ++c) {
        const double xv = xbuf[c][kk];
#pragma unroll
        for (int j = 0; j < 4; ++j) a2[j][c] = fma(w[j], xv, a2[j][c]);
      }
      wf = wfn;
    }
  }

  // head weights for this thread's 4 co's
  const float4 bff = *(const float4*)&bfc[tid << 2];
  const float4 wsf = *(const float4*)&Wsc[tid << 2];
  const float4 wr01 = *(const float4*)&Wrg[(tid << 3)];
  const float4 wr23 = *(const float4*)&Wrg[(tid << 3) + 4];
  const double bfv[4] = {(double)bff.x, (double)bff.y, (double)bff.z, (double)bff.w};
  const double wsv[4] = {(double)wsf.x, (double)wsf.y, (double)wsf.z, (double)wsf.w};
  const double w0v[4] = {(double)wr01.x, (double)wr01.z, (double)wr23.x, (double)wr23.z};
  const double w1v[4] = {(double)wr01.y, (double)wr01.w, (double)wr23.y, (double)wr23.w};

  __syncthreads();
  for (int c = 0; c < RC2; ++c) {
    double s = 0.0, ry = 0.0, rx = 0.0;
#pragma unroll
    for (int j = 0; j < 4; ++j) {
      double v = a2[j][c] + bfv[j];
      v = v > 0.0 ? v : 0.0;
      s  = fma(v, wsv[j], s);
      ry = fma(v, w0v[j], ry);
      rx = fma(v, w1v[j], rx);
    }
    for (int h = 0; h < 3; ++h) {
      redd[tid] = (h == 0) ? s : (h == 1) ? ry : rx;
      __syncthreads();
      for (int st = 128; st > 0; st >>= 1) {
        if (tid < st) redd[tid] += redd[tid + st];
        __syncthreads();
      }
      if (tid == 0 && c0 + c < cnt) {
        const double tot = redd[0];
        if (h == 0) {
          const double lg = tot + (double)bs[0];
          const double sg = 1.0 / (1.0 + exp(-lg));
          cand_sb[c0 + c] = (unsigned long long)__double_as_longlong(sg);
        } else if (h == 1) cand_ry[c0 + c] = tot + (double)br[0];
        else               cand_rx[c0 + c] = tot + (double)br[1];
      }
      __syncthreads();
    }
  }
}

// ---------------------------------------------------------------------------
// proposal: f64 radix-select top-2000 among candidates, sort 2048, f64 NMS,
// emit outputs.  Single block, 1024 threads.
// ---------------------------------------------------------------------------
__global__ __launch_bounds__(1024) void proposal_kernel(
    const unsigned int* __restrict__ cand_idx,
    const unsigned int* __restrict__ cand_cnt,
    const unsigned long long* __restrict__ cand_sb,
    const double* __restrict__ cand_ry, const double* __restrict__ cand_rx,
    unsigned int* __restrict__ cellrank, unsigned int* __restrict__ nbrg,
    double* __restrict__ cyg, double* __restrict__ cxg,
    int* __restrict__ startb, float* __restrict__ out_ps,
    float* __restrict__ out_dec)
{
  __shared__ unsigned long long sk[2048];
  __shared__ unsigned int si[2048];
  __shared__ unsigned int hist[256];
  __shared__ unsigned long long sh_pref;
  __shared__ unsigned int cnt_a, cnt_b;
  __shared__ unsigned char kept[2048];
  __shared__ unsigned char nbrc[2048];
  __shared__ int scan[2048];
  __shared__ volatile unsigned int changed;
  __shared__ int sh_maxreg;

  const int tid = threadIdx.x;
  const int cnt = (int)*cand_cnt;

  for (int i = tid; i < 65536; i += 1024) cellrank[i] = 0xFFFFFFFFu;

  unsigned long long prefix = 0ull;
  int need = KTOP;
  for (int byte = 7; byte >= 0; --byte) {
    if (tid < 256) hist[tid] = 0u;
    __syncthreads();
    const int sh = byte * 8;
    const unsigned long long mhi =
        (byte == 7) ? 0ull : (0xFFFFFFFFFFFFFFFFull << (sh + 8));
    for (int i = tid; i < cnt; i += 1024) {
      const unsigned long long k = cand_sb[i];
      if ((k & mhi) == prefix) atomicAdd(&hist[(unsigned int)((k >> sh) & 255u)], 1u);
    }
    __syncthreads();
    if (tid == 0) {
      int cum = 0;
      for (int v = 255; v >= 0; --v) {
        const int c = (int)hist[v];
        if (cum + c >= need) {
          sh_pref = prefix | ((unsigned long long)(unsigned)v << sh);
          break;
        }
        cum += c;
      }
      hist[0] = (unsigned int)cum;
    }
    __syncthreads();
    prefix = sh_pref;
    need -= (int)hist[0];
    __syncthreads();
  }
  const unsigned long long T = prefix;

  if (tid == 0) { cnt_a = 0; cnt_b = 0; }
  __syncthreads();
  for (int i = tid; i < cnt; i += 1024) {
    const unsigned long long k = cand_sb[i];
    if (k > T) {
      const unsigned int p = atomicAdd(&cnt_a, 1u);
      if (p < KTOP) { sk[p] = k; si[p] = (unsigned int)i; }
    }
  }
  __syncthreads();
  const unsigned int base = cnt_a;
  for (int i = tid; i < cnt; i += 1024) {
    const unsigned long long k = cand_sb[i];
    if (k == T) {
      const unsigned int p = base + atomicAdd(&cnt_b, 1u);
      if (p < KTOP) { sk[p] = k; si[p] = (unsigned int)i; }
    }
  }
  __syncthreads();
  for (int i = tid; i < 2048; i += 1024)
    if (i >= KTOP) { sk[i] = 0ull; si[i] = 0u; }
  if (tid == 0) sh_maxreg = 0;
  __syncthreads();

  for (int k = 2; k <= 2048; k <<= 1) {
    for (int j = k >> 1; j > 0; j >>= 1) {
      const int i = (tid & (j - 1)) | ((tid & ~(j - 1)) << 1);
      const int ixj = i | j;
      const unsigned long long a = sk[i], b = sk[ixj];
      const bool up = ((i & k) == 0);
      if (up ? (a < b) : (a > b)) {
        sk[i] = b; sk[ixj] = a;
        const unsigned int t = si[i]; si[i] = si[ixj]; si[ixj] = t;
      }
      __syncthreads();
    }
  }

  for (int r = tid; r < KTOP; r += 1024) {
    const unsigned int slot = si[r];
    const unsigned int idx = cand_idx[slot];
    const int row = (int)(idx >> 8), col = (int)(idx & 255u);
    const double ry = cand_ry[slot], rx = cand_rx[slot];
    cyg[r] = ((double)row + 0.5) + ry;
    cxg[r] = ((double)col + 0.5) + rx;
    kept[r] = 1; nbrc[r] = 0;
    cellrank[idx] = (unsigned int)r;
    atomicMax(&sh_maxreg, __float_as_int((float)fabs(ry)));
    atomicMax(&sh_maxreg, __float_as_int((float)fabs(rx)));
  }
  __syncthreads();
  const float maxreg = __int_as_float(sh_maxreg);
  int rad = (int)(1.0f + 2.0f * maxreg) + 1;
  if (rad > 8) rad = 8;
  if (rad < 1) rad = 1;

  for (int r = tid; r < KTOP; r += 1024) {
    const unsigned int idx = cand_idx[si[r]];
    const int row = (int)(idx >> 8), col = (int)(idx & 255u);
    int n = 0;
    const double pyr = cyg[r], pxr = cxg[r];
    for (int dy = -rad; dy <= rad; ++dy) {
      const int yy = row + dy; if (yy < 0 || yy >= 256) continue;
      for (int dx = -rad; dx <= rad; ++dx) {
        if (dy == 0 && dx == 0) continue;
        const int xx = col + dx; if (xx < 0 || xx >= 256) continue;
        const unsigned int q = cellrank[yy * 256 + xx];
        if (q < (unsigned int)r) {
          const double t1 = __dsub_rn(pyr, cyg[q]);
          const double t2 = __dsub_rn(pxr, cxg[q]);
          const double d2 = __dadd_rn(__dmul_rn(t1, t1), __dmul_rn(t2, t2));
          if (d2 < 1.0) { if (n < 16) nbrg[(size_t)r * 16 + n] = q; ++n; }
        }
      }
    }
    nbrc[r] = (unsigned char)(n < 16 ? n : 16);
  }
  __syncthreads();

  for (int it = 0; it < 4096; ++it) {
    __syncthreads();
    if (tid == 0) changed = 0;
    __syncthreads();
    for (int r = tid; r < KTOP; r += 1024) {
      const int nc = nbrc[r];
      if (nc) {
        int kv = 1;
        for (int t = 0; t < nc; ++t)
          if (kept[nbrg[(size_t)r * 16 + t]]) { kv = 0; break; }
        if (kv != (int)kept[r]) { kept[r] = (unsigned char)kv; changed = 1; }
      }
    }
    __syncthreads();
    if (changed == 0) break;
  }

  scan[tid]        = (tid < KTOP) ? (int)kept[tid] : 0;
  scan[tid + 1024] = (tid + 1024 < KTOP) ? (int)kept[tid + 1024] : 0;
  __syncthreads();
  for (int off = 1; off < 2048; off <<= 1) {
    const int a0 = scan[tid];
    const int b0 = (tid >= off) ? scan[tid - off] : 0;
    const int a1 = scan[tid + 1024];
    const int b1 = (tid + 1024 >= off) ? scan[tid + 1024 - off] : 0;
    __syncthreads();
    scan[tid] = a0 + b0;
    scan[tid + 1024] = a1 + b1;
    __syncthreads();
  }
  const int total = scan[KTOP - 1];

  for (int r = tid; r < KTOP; r += 1024) {
    int slot = -1;
    if (kept[r]) { const int p = scan[r] - 1; if (p < MAXOUT) slot = p; }
    else { const int p = total + (r - scan[r]); if (p < MAXOUT) slot = p; }
    if (slot >= 0) {
      const double sg = __longlong_as_double((long long)sk[r]);
      out_ps[slot] = kept[r] ? (float)sg : -1.0f;
      const double py = cyg[r], px = cxg[r];
      out_dec[slot * 2]     = (float)(py * 4.0);
      out_dec[slot * 2 + 1] = (float)(px * 4.0);
      int sy = (int)rint(py * 2.0 - 24.0);
      int sx = (int)rint(px * 2.0 - 24.0);
      sy = sy < 0 ? 0 : (sy > 464 ? 464 : sy);
      sx = sx < 0 ? 0 : (sx > 464 ? 464 : sx);
      startb[slot * 2] = sy; startb[slot * 2 + 1] = sx;
    }
  }
}

// ---------------------------------------------------------------------------
// instance conv_i: 3x3, 32->64 + relu on 48x48 crops.  h chunk-local.
// ---------------------------------------------------------------------------
__global__ __launch_bounds__(256) void conv_i_kernel(
    const float* __restrict__ seg, const float* __restrict__ Wi,
    const float* __restrict__ bi, const int* __restrict__ startb,
    float* __restrict__ h, int inst0)
{
  __shared__ float ins[32 * 325];
  __shared__ float wis[288 * 16];
  const int li = blockIdx.y;
  const int inst = inst0 + li;
  const int ti = blockIdx.x >> 2;
  const int cobase = (blockIdx.x & 3) << 4;
  const int y0 = (ti / 3) << 4;
  const int x0 = (ti % 3) << 4;
  const int tid = threadIdx.x;
  const int sy = startb[inst * 2], sx = startb[inst * 2 + 1];

  for (int idx = tid; idx < 288 * 16; idx += 256) {
    const int k = idx >> 4, co = idx & 15;
    wis[idx] = Wi[(size_t)k * 64 + cobase + co];
  }
  for (int idx = tid; idx < 18 * 18 * 32; idx += 256) {
    const int c = idx & 31;
    const int rem = idx >> 5;
    const int ix = rem % 18, iy = rem / 18;
    const int cyy = y0 - 1 + iy, cxx = x0 - 1 + ix;
    float v = 0.f;
    if (cyy >= 0 && cyy < 48 && cxx >= 0 && cxx < 48)
      v = seg[((size_t)(sy + cyy) * 512 + (sx + cxx)) * 32 + c];
    ins[c * 325 + iy * 18 + ix] = v;
  }
  __syncthreads();

  const int co4 = tid & 3;
  const int posg = tid >> 2;
  const int ly = posg >> 2;
  const int lx0 = (posg & 3) << 2;
  float acc[4][4];
#pragma unroll
  for (int q = 0; q < 4; ++q)
#pragma unroll
    for (int j = 0; j < 4; ++j) acc[q][j] = 0.f;

  for (int ky = 0; ky < 3; ++ky)
    for (int kx = 0; kx < 3; ++kx) {
#pragma unroll 4
      for (int ci = 0; ci < 32; ++ci) {
        const float* ip = &ins[ci * 325 + (ly + ky) * 18 + lx0 + kx];
        const float4 wv = *(const float4*)&wis[(((ky * 3 + kx) * 32 + ci) << 4) + (co4 << 2)];
#pragma unroll
        for (int q = 0; q < 4; ++q) {
          const float iv = ip[q];
          acc[q][0] = fmaf(iv, wv.x, acc[q][0]);
          acc[q][1] = fmaf(iv, wv.y, acc[q][1]);
          acc[q][2] = fmaf(iv, wv.z, acc[q][2]);
          acc[q][3] = fmaf(iv, wv.w, acc[q][3]);
        }
      }
    }

  const float4 bv = *(const float4*)&bi[cobase + (co4 << 2)];
#pragma unroll
  for (int q = 0; q < 4; ++q) {
    const int gy = y0 + ly, gx = x0 + lx0 + q;
    float4 o;
    o.x = fmaxf(acc[q][0] + bv.x, 0.f);
    o.y = fmaxf(acc[q][1] + bv.y, 0.f);
    o.z = fmaxf(acc[q][2] + bv.z, 0.f);
    o.w = fmaxf(acc[q][3] + bv.w, 0.f);
    *(float4*)&h[(((size_t)li * 48 + gy) * 48 + gx) * 64 + cobase + (co4 << 2)] = o;
  }
}

// ---------------------------------------------------------------------------
// instance conv_o: 3x3, 64->1 + sigmoid; also emits instance_coords.
// ---------------------------------------------------------------------------
__global__ __launch_bounds__(128) void conv_o_kernel(
    const float* __restrict__ h, const float* __restrict__ Wo,
    const float* __restrict__ bo, const int* __restrict__ startb,
    float* __restrict__ out_io, float* __restrict__ out_ic, int inst0)
{
  __shared__ float hs[10 * 18 * 65];
  __shared__ float wos[576];
  const int li = blockIdx.y;
  const int inst = inst0 + li;
  const int tile = blockIdx.x;
  const int ty0 = (tile / 3) * 8;
  const int tx0 = (tile % 3) * 16;
  const int tid = threadIdx.x;

  for (int i = tid; i < 576; i += 128) wos[i] = Wo[i];
  for (int idx = tid; idx < 10 * 18 * 64; idx += 128) {
    const int co = idx & 63;
    const int rem = idx >> 6;
    const int ix = rem % 18, iy = rem / 18;
    const int gy = ty0 - 1 + iy, gx = tx0 - 1 + ix;
    float v = 0.f;
    if (gy >= 0 && gy < 48 && gx >= 0 && gx < 48)
      v = h[(((size_t)li * 48 + gy) * 48 + gx) * 64 + co];
    hs[(iy * 18 + ix) * 65 + co] = v;
  }
  __syncthreads();

  const int ly = tid >> 4, lx = tid & 15;
  float a = 0.f;
#pragma unroll
  for (int ky = 0; ky < 3; ++ky)
#pragma unroll
    for (int kx = 0; kx < 3; ++kx) {
      const float* hp = &hs[((ly + ky) * 18 + (lx + kx)) * 65];
      const float* wp = &wos[(ky * 3 + kx) * 64];
#pragma unroll
      for (int c = 0; c < 64; ++c) a = fmaf(hp[c], wp[c], a);
    }
  a += bo[0];
  const float o = 1.f / (1.f + expf(-a));
  const int gy = ty0 + ly, gx = tx0 + lx;
  const size_t p = ((size_t)inst * 48 + gy) * 48 + gx;
  out_io[p] = o;
  const int sy = startb[inst * 2], sx = startb[inst * 2 + 1];
  out_ic[p * 2]     = (float)(sy + gy);
  out_ic[p * 2 + 1] = (float)(sx + gx);
}

// ---------------------------------------------------------------------------
extern "C" void kernel_launch(void* const* d_in, const int* in_sizes, int n_in,
                              void* d_out, int out_size, void* d_ws, size_t ws_size,
                              hipStream_t stream)
{
  const float* df  = (const float*)d_in[0];
  const float* seg = (const float*)d_in[1];
  const float* Wc  = (const float*)d_in[2];
  const float* bc  = (const float*)d_in[3];
  const float* Wfc = (const float*)d_in[4];
  const float* bfc = (const float*)d_in[5];
  const float* Wsc = (const float*)d_in[6];
  const float* bs  = (const float*)d_in[7];
  const float* Wrg = (const float*)d_in[8];
  const float* br  = (const float*)d_in[9];
  const float* Wi  = (const float*)d_in[10];
  const float* bi  = (const float*)d_in[11];
  const float* Wo  = (const float*)d_in[12];
  const float* bo  = (const float*)d_in[13];

  const size_t SZ_WCT = 2359296ull, SZ_WFT = 2097152ull, SZ_PART = 2097152ull,
               SZ_SC = 262144ull, SZ_CR = 262144ull, SZ_NB = 131072ull,
               SZ_STB = 4096ull, SZ_CI = CANDCAP * 4ull, SZ_SB = CANDCAP * 8ull,
               SZ_RY = CANDCAP * 8ull, SZ_RX = CANDCAP * 8ull,
               SZ_CY = 16384ull, SZ_CX = 16384ull, SZ_CNT = 256ull;
  const size_t FIXED = SZ_WCT + SZ_WFT + SZ_PART + SZ_SC + SZ_CR + SZ_NB +
                       SZ_STB + SZ_CI + SZ_SB + SZ_RY + SZ_RX + SZ_CY + SZ_CX + SZ_CNT;
  char* w = (char*)d_ws;
  size_t region = (ws_size > FIXED) ? ((ws_size - FIXED) & ~(size_t)255) : 0;
  char* fb = w + region;
  unsigned short* WcT = (unsigned short*)fb;   fb += SZ_WCT;
  unsigned short* WfcT = (unsigned short*)fb;  fb += SZ_WFT;
  float* part = (float*)fb;                    fb += SZ_PART;
  float* scores = (float*)fb;                  fb += SZ_SC;
  unsigned int* cellrank = (unsigned int*)fb;  fb += SZ_CR;
  unsigned int* nbrg = (unsigned int*)fb;      fb += SZ_NB;
  int* startb = (int*)fb;                      fb += SZ_STB;
  unsigned int* cand_idx = (unsigned int*)fb;  fb += SZ_CI;
  unsigned long long* cand_sb = (unsigned long long*)fb; fb += SZ_SB;
  double* cand_ry = (double*)fb;               fb += SZ_RY;
  double* cand_rx = (double*)fb;               fb += SZ_RX;
  double* cyg = (double*)fb;                   fb += SZ_CY;
  double* cxg = (double*)fb;                   fb += SZ_CX;
  unsigned int* cand_cnt = (unsigned int*)fb;
  unsigned short* x1b = (unsigned short*)w;    // big region: bf16 x1 chunk
  double* x1g = (double*)w;                    // big region: f64 x1 (33.5 MB)
  float* hb = (float*)w;                       // big region: inst crops

  size_t tiles_fit = region / 131072ull;
  int pt_chunk = 2;
  while ((size_t)(pt_chunk * 2) <= tiles_fit && pt_chunk < 1024) pt_chunk <<= 1;
  size_t inst_fit = region / 589824ull;
  const int opts[12] = {500, 250, 125, 100, 50, 25, 20, 10, 5, 4, 2, 1};
  int inst_chunk = 1;
  for (int o = 0; o < 12; ++o)
    if ((size_t)opts[o] <= inst_fit) { inst_chunk = opts[o]; break; }

  float* out = (float*)d_out;
  float* out_ps  = out;
  float* out_dec = out + 500;
  float* out_io  = out + 1500;
  float* out_ic  = out + 1153500;

  transpose_bf16_kernel<<<dim3(36, 32), 256, 0, stream>>>(Wc, WcT, 1152, 1024);
  transpose_bf16_kernel<<<dim3(32, 32), 256, 0, stream>>>(Wfc, WfcT, 1024, 1024);

  for (int c = 0; c < 1024 / pt_chunk; ++c) {
    conv1_mfma<<<dim3(8, pt_chunk / 2), 256, 0, stream>>>(df, WcT, bc, x1b,
                                                          c * pt_chunk);
    fc_mfma<<<dim3(8, pt_chunk / 2), 256, 0, stream>>>(x1b, WfcT, bfc, Wsc,
                                                       part, c * pt_chunk);
  }
  head_finalize_kernel<<<256, 256, 0, stream>>>(part, bs, scores);
  select_kernel<<<1, 1024, 0, stream>>>(scores, cand_idx, cand_cnt);
  rescore_conv<<<CANDCAP / RC2, 256, 0, stream>>>(df, Wc, bc, cand_idx,
                                                  cand_cnt, x1g);
  rescore_fc<<<CANDCAP / RC2, 256, 0, stream>>>(x1g, Wfc, bfc, Wsc, bs, Wrg,
                                                br, cand_cnt, cand_sb,
                                                cand_ry, cand_rx);
  proposal_kernel<<<1, 1024, 0, stream>>>(cand_idx, cand_cnt, cand_sb, cand_ry,
                                          cand_rx, cellrank, nbrg, cyg, cxg,
                                          startb, out_ps, out_dec);
  for (int c = 0; c < 500 / inst_chunk; ++c) {
    conv_i_kernel<<<dim3(36, inst_chunk), 256, 0, stream>>>(seg, Wi, bi, startb,
                                                            hb, c * inst_chunk);
    conv_o_kernel<<<dim3(18, inst_chunk), 128, 0, stream>>>(hb, Wo, bo, startb,
                                                            out_io, out_ic,
                                                            c * inst_chunk);
  }
}

// Round 8
// 2058.718 us; speedup vs baseline: 1.5664x; 1.5664x over previous
//
#include <hip/hip_runtime.h>
#include <math.h>

#define KTOP 2000
#define MAXOUT 500
#define CANDCAP 4096          // candidate capacity (global buffers)
#define NSEL 3600             // approx-score rank margin for selection
#define RC2 16                // candidates per rescore block (256 groups)

typedef __attribute__((ext_vector_type(8))) short short8;
typedef __attribute__((ext_vector_type(4))) float f32x4;

__device__ __forceinline__ unsigned short f2bf(float f) {
  unsigned int u = __float_as_uint(f);
  unsigned int r = ((u >> 16) & 1u) + 0x7FFFu;
  return (unsigned short)((u + r) >> 16);
}

// ---------------------------------------------------------------------------
// transpose+convert: W[K][N] f32 -> WT[N][K] bf16.  grid (K/32, N/32), 256 thr
// ---------------------------------------------------------------------------
__global__ __launch_bounds__(256) void transpose_bf16_kernel(
    const float* __restrict__ W, unsigned short* __restrict__ WT, int K, int N)
{
  __shared__ float t[32][33];
  const int k0 = blockIdx.x << 5, n0 = blockIdx.y << 5;
  const int tid = threadIdx.x;
  const int r = tid >> 5, c = tid & 31;
#pragma unroll
  for (int p = 0; p < 4; ++p)
    t[r + (p << 3)][c] = W[(size_t)(k0 + r + (p << 3)) * N + n0 + c];
  __syncthreads();
#pragma unroll
  for (int p = 0; p < 4; ++p)
    WT[(size_t)(n0 + r + (p << 3)) * K + k0 + c] = f2bf(t[c][r + (p << 3)]);
}

// ---------------------------------------------------------------------------
// prep WiB: Wi[288][64] f32 -> WiB[tap(9)][co(64)][ci(32)] bf16
// ---------------------------------------------------------------------------
__global__ __launch_bounds__(256) void prep_wib_kernel(
    const float* __restrict__ Wi, unsigned short* __restrict__ WiB)
{
  const int t = blockIdx.x * 256 + threadIdx.x;
  if (t < 9 * 64 * 32) {
    const int tap = t / 2048, r = t & 2047, co = r >> 5, ci = r & 31;
    WiB[t] = f2bf(Wi[((size_t)tap * 32 + ci) * 64 + co]);
  }
}

// ---------------------------------------------------------------------------
// conv1 via bf16 MFMA: 3x3 128->1024 + bias + relu -> x1b (bf16, chunk-local)
// ---------------------------------------------------------------------------
#define LSTR 72   // LDS row stride in bf16 elements (144 B)
__global__ __launch_bounds__(256) void conv1_mfma(
    const float* __restrict__ df, const unsigned short* __restrict__ WcT,
    const float* __restrict__ bc, unsigned short* __restrict__ x1b, int pt0)
{
  __shared__ __align__(16) unsigned short As[128 * LSTR];
  __shared__ __align__(16) unsigned short Bs[128 * LSTR];
  const int tid = threadIdx.x;
  const int n0 = blockIdx.x << 7;
  const int m0 = blockIdx.y << 7;
  const int Pbase = (pt0 << 6) + m0;
  const int ybase = Pbase >> 8, x0 = Pbase & 255;
  const int wv = tid >> 6, lane = tid & 63;
  const int wm = (wv & 1) << 6, wn = (wv >> 1) << 6;
  const int l15 = lane & 15, quad = lane >> 4;

  f32x4 acc[4][4];
  const f32x4 z4 = {0.f, 0.f, 0.f, 0.f};
#pragma unroll
  for (int i = 0; i < 4; ++i)
#pragma unroll
    for (int j = 0; j < 4; ++j) acc[i][j] = z4;

  for (int kc = 0; kc < 18; ++kc) {
    const int tap = kc >> 1, ci0 = (kc & 1) << 6;
    const int dy = tap / 3 - 1, dx = tap % 3 - 1;
    const int gy = ybase + dy;
    const bool yok = (gy >= 0 && gy < 256);
#pragma unroll
    for (int p = 0; p < 8; ++p) {
      const int r = (p << 4) + (tid >> 4);
      const int c4 = tid & 15;
      const int gx = x0 + r + dx;
      float4 v = make_float4(0.f, 0.f, 0.f, 0.f);
      if (yok && gx >= 0 && gx < 256)
        v = *(const float4*)&df[((size_t)((gy << 8) + gx)) * 128 + ci0 + (c4 << 2)];
      const unsigned int lo = (unsigned int)f2bf(v.x) | ((unsigned int)f2bf(v.y) << 16);
      const unsigned int hi = (unsigned int)f2bf(v.z) | ((unsigned int)f2bf(v.w) << 16);
      *(uint2*)&As[r * LSTR + (c4 << 2)] = make_uint2(lo, hi);
    }
#pragma unroll
    for (int p = 0; p < 4; ++p) {
      const int n = (p << 5) + (tid >> 3);
      const int kg = (tid & 7) << 3;
      const uint4 w = *(const uint4*)&WcT[(size_t)(n0 + n) * 1152 + kc * 64 + kg];
      *(uint4*)&Bs[n * LSTR + kg] = w;
    }
    __syncthreads();
#pragma unroll
    for (int s = 0; s < 2; ++s) {
      short8 a[4], b[4];
#pragma unroll
      for (int i = 0; i < 4; ++i)
        a[i] = *(short8*)&As[(wm + (i << 4) + l15) * LSTR + (s << 5) + (quad << 3)];
#pragma unroll
      for (int i = 0; i < 4; ++i)
        b[i] = *(short8*)&Bs[(wn + (i << 4) + l15) * LSTR + (s << 5) + (quad << 3)];
#pragma unroll
      for (int i = 0; i < 4; ++i)
#pragma unroll
        for (int j = 0; j < 4; ++j)
          acc[i][j] = __builtin_amdgcn_mfma_f32_16x16x32_bf16(a[i], b[j], acc[i][j], 0, 0, 0);
    }
    __syncthreads();
  }
#pragma unroll
  for (int i = 0; i < 4; ++i)
#pragma unroll
    for (int j = 0; j < 4; ++j) {
      const int col = wn + (j << 4) + l15;
      const float bb = bc[n0 + col];
#pragma unroll
      for (int rg = 0; rg < 4; ++rg) {
        const int row = wm + (i << 4) + (quad << 2) + rg;
        const float v = fmaxf(acc[i][j][rg] + bb, 0.f);
        x1b[(size_t)(m0 + row) * 1024 + n0 + col] = f2bf(v);
      }
    }
}

// ---------------------------------------------------------------------------
// fc via bf16 MFMA: 1x1 1024->1024 + bias + relu, fused score partials.
// ---------------------------------------------------------------------------
__global__ __launch_bounds__(256) void fc_mfma(
    const unsigned short* __restrict__ x1b, const unsigned short* __restrict__ WfcT,
    const float* __restrict__ bfc, const float* __restrict__ Wsc,
    float* __restrict__ part, int pt0)
{
  __shared__ __align__(16) unsigned short As[128 * LSTR];
  __shared__ __align__(16) unsigned short Bs[128 * LSTR];
  const int tid = threadIdx.x;
  const int n0 = blockIdx.x << 7;
  const int m0 = blockIdx.y << 7;
  const int Pbase = (pt0 << 6) + m0;
  const int wv = tid >> 6, lane = tid & 63;
  const int wm = (wv & 1) << 6, wn = (wv >> 1) << 6;
  const int l15 = lane & 15, quad = lane >> 4;

  f32x4 acc[4][4];
  const f32x4 z4 = {0.f, 0.f, 0.f, 0.f};
#pragma unroll
  for (int i = 0; i < 4; ++i)
#pragma unroll
    for (int j = 0; j < 4; ++j) acc[i][j] = z4;

  for (int kc = 0; kc < 16; ++kc) {
#pragma unroll
    for (int p = 0; p < 4; ++p) {
      const int r = (p << 5) + (tid >> 3);
      const int kg = (tid & 7) << 3;
      const uint4 w = *(const uint4*)&x1b[(size_t)(m0 + r) * 1024 + kc * 64 + kg];
      *(uint4*)&As[r * LSTR + kg] = w;
    }
#pragma unroll
    for (int p = 0; p < 4; ++p) {
      const int n = (p << 5) + (tid >> 3);
      const int kg = (tid & 7) << 3;
      const uint4 w = *(const uint4*)&WfcT[(size_t)(n0 + n) * 1024 + kc * 64 + kg];
      *(uint4*)&Bs[n * LSTR + kg] = w;
    }
    __syncthreads();
#pragma unroll
    for (int s = 0; s < 2; ++s) {
      short8 a[4], b[4];
#pragma unroll
      for (int i = 0; i < 4; ++i)
        a[i] = *(short8*)&As[(wm + (i << 4) + l15) * LSTR + (s << 5) + (quad << 3)];
#pragma unroll
      for (int i = 0; i < 4; ++i)
        b[i] = *(short8*)&Bs[(wn + (i << 4) + l15) * LSTR + (s << 5) + (quad << 3)];
#pragma unroll
      for (int i = 0; i < 4; ++i)
#pragma unroll
        for (int j = 0; j < 4; ++j)
          acc[i][j] = __builtin_amdgcn_mfma_f32_16x16x32_bf16(a[i], b[j], acc[i][j], 0, 0, 0);
    }
    __syncthreads();
  }
  float wsv[4], bfv[4];
#pragma unroll
  for (int j = 0; j < 4; ++j) {
    const int col = n0 + wn + (j << 4) + l15;
    wsv[j] = Wsc[col];
    bfv[j] = bfc[col];
  }
  float* red = (float*)As;
#pragma unroll
  for (int i = 0; i < 4; ++i)
#pragma unroll
    for (int rg = 0; rg < 4; ++rg) {
      const int row = wm + (i << 4) + (quad << 2) + rg;
      float ps = 0.f;
#pragma unroll
      for (int j = 0; j < 4; ++j) {
        const float v = fmaxf(acc[i][j][rg] + bfv[j], 0.f);
        ps = fmaf(v, wsv[j], ps);
      }
      red[row * 33 + ((wv >> 1) << 4) + l15] = ps;
    }
  __syncthreads();
  if (tid < 128) {
    float s = 0.f;
#pragma unroll
    for (int sl = 0; sl < 32; ++sl) s += red[tid * 33 + sl];
    part[(size_t)blockIdx.x * 65536 + Pbase + tid] = s;
  }
}

// ---------------------------------------------------------------------------
// finalize: sum 8 partials, bias, sigmoid -> f32 approx scores (selection)
// ---------------------------------------------------------------------------
__global__ __launch_bounds__(256) void head_finalize_kernel(
    const float* __restrict__ part, const float* __restrict__ bs,
    float* __restrict__ scores)
{
  const int pix = blockIdx.x * 256 + threadIdx.x;
  float s = 0.f;
#pragma unroll
  for (int cb = 0; cb < 8; ++cb) s += part[(size_t)cb * 65536 + pix];
  s += bs[0];
  scores[pix] = 1.f / (1.f + expf(-s));
}

// ---------------------------------------------------------------------------
// select: radix-select NSEL-th approx score, then DETERMINISTIC prefix-scan
// compaction of all cells >= thr in ascending cell order (no atomics).
// ---------------------------------------------------------------------------
__global__ __launch_bounds__(1024) void select_kernel(
    const float* __restrict__ scores, unsigned int* __restrict__ cand_idx,
    unsigned int* __restrict__ cand_cnt)
{
  __shared__ unsigned int hist[256];
  __shared__ unsigned int sh_prefix;
  __shared__ int scan_s[1024];
  const int tid = threadIdx.x;

  unsigned int prefix = 0u;
  int need = NSEL;
  for (int byte = 3; byte >= 0; --byte) {
    if (tid < 256) hist[tid] = 0u;
    __syncthreads();
    const int sh = byte * 8;
    const unsigned int mhi = (byte == 3) ? 0u : (0xFFFFFFFFu << (sh + 8));
    for (int i = tid; i < 65536; i += 1024) {
      const unsigned int b = __float_as_uint(scores[i]);
      if ((b & mhi) == prefix) atomicAdd(&hist[(b >> sh) & 255u], 1u);
    }
    __syncthreads();
    if (tid == 0) {
      int cum = 0;
      for (int v = 255; v >= 0; --v) {
        const int c = (int)hist[v];
        if (cum + c >= need) { sh_prefix = prefix | ((unsigned)v << sh); break; }
        cum += c;
      }
      hist[0] = (unsigned int)cum;
    }
    __syncthreads();
    prefix = sh_prefix;
    need -= (int)hist[0];
    __syncthreads();
  }
  const float thr = __uint_as_float(prefix);

  // deterministic compaction: thread t owns cells [t*64, t*64+64)
  const int b0 = tid << 6;
  int my = 0;
  for (int k = 0; k < 64; ++k)
    if (scores[b0 + k] >= thr) ++my;
  scan_s[tid] = my;
  __syncthreads();
  for (int off = 1; off < 1024; off <<= 1) {
    const int a = scan_s[tid];
    const int b = (tid >= off) ? scan_s[tid - off] : 0;
    __syncthreads();
    scan_s[tid] = a + b;
    __syncthreads();
  }
  int pos = scan_s[tid] - my;     // exclusive prefix
  const int total = scan_s[1023];
  for (int k = 0; k < 64; ++k) {
    if (scores[b0 + k] >= thr) {
      if (pos < CANDCAP) cand_idx[pos] = (unsigned int)(b0 + k);
      ++pos;
    }
  }
  if (tid == 0)
    *cand_cnt = (unsigned int)(total > CANDCAP ? CANDCAP : total);
}

// ---------------------------------------------------------------------------
// rescore_conv: f64 conv1 for RC2 candidates per block -> x1g (global f64).
// ---------------------------------------------------------------------------
__global__ __launch_bounds__(256) void rescore_conv(
    const float* __restrict__ df, const float* __restrict__ Wc,
    const float* __restrict__ bc,
    const unsigned int* __restrict__ cand_idx,
    const unsigned int* __restrict__ cand_cnt,
    double* __restrict__ x1g)
{
  __shared__ float patt[RC2][132];
  const int cnt = (int)*cand_cnt;
  const int c0 = blockIdx.x * RC2;
  if (c0 >= cnt) return;
  const int tid = threadIdx.x;

  int rr[RC2], cc[RC2];
#pragma unroll
  for (int c = 0; c < RC2; ++c) {
    const int slot = (c0 + c < cnt) ? c0 + c : c0;
    const unsigned int idx = cand_idx[slot];
    rr[c] = (int)(idx >> 8); cc[c] = (int)(idx & 255u);
  }

  double acc[4][RC2];
#pragma unroll
  for (int j = 0; j < 4; ++j)
#pragma unroll
    for (int c = 0; c < RC2; ++c) acc[j][c] = 0.0;

  for (int tap = 0; tap < 9; ++tap) {
    const int dy = tap / 3 - 1, dx = tap % 3 - 1;
    for (int t = tid; t < RC2 * 128; t += 256) {
      const int c = t >> 7, ci = t & 127;
      const int gy = rr[c] + dy, gx = cc[c] + dx;
      float v = 0.f;
      if (gy >= 0 && gy < 256 && gx >= 0 && gx < 256)
        v = df[((size_t)((gy << 8) + gx)) * 128 + ci];
      patt[c][ci] = v;
    }
    __syncthreads();
    const float* wbase = &Wc[(size_t)(tap << 7) * 1024 + (tid << 2)];
    float4 wf = *(const float4*)wbase;
    for (int ci = 0; ci < 128; ++ci) {
      const float4 wfn = (ci + 1 < 128)
          ? *(const float4*)(wbase + (size_t)(ci + 1) * 1024) : wf;
      double w[4];
      w[0] = (double)wf.x; w[1] = (double)wf.y;
      w[2] = (double)wf.z; w[3] = (double)wf.w;
#pragma unroll
      for (int c = 0; c < RC2; ++c) {
        const double p = (double)patt[c][ci];
#pragma unroll
        for (int j = 0; j < 4; ++j) acc[j][c] = fma(w[j], p, acc[j][c]);
      }
      wf = wfn;
    }
    __syncthreads();
  }
  const float4 bf4 = *(const float4*)&bc[tid << 2];
  const double b4[4] = {(double)bf4.x, (double)bf4.y, (double)bf4.z, (double)bf4.w};
#pragma unroll
  for (int c = 0; c < RC2; ++c) {
    if (c0 + c < cnt) {
      double v0 = acc[0][c] + b4[0]; v0 = v0 > 0.0 ? v0 : 0.0;
      double v1 = acc[1][c] + b4[1]; v1 = v1 > 0.0 ? v1 : 0.0;
      double v2 = acc[2][c] + b4[2]; v2 = v2 > 0.0 ? v2 : 0.0;
      double v3 = acc[3][c] + b4[3]; v3 = v3 > 0.0 ? v3 : 0.0;
      double2* o = (double2*)&x1g[(size_t)(c0 + c) * 1024 + (tid << 2)];
      o[0] = make_double2(v0, v1);
      o[1] = make_double2(v2, v3);
    }
  }
}

// ---------------------------------------------------------------------------
// rescore_fc: f64 fc + heads for RC2 candidates per block, x1 from x1g.
// ---------------------------------------------------------------------------
__global__ __launch_bounds__(256) void rescore_fc(
    const double* __restrict__ x1g, const float* __restrict__ Wfc,
    const float* __restrict__ bfc, const float* __restrict__ Wsc,
    const float* __restrict__ bs, const float* __restrict__ Wrg,
    const float* __restrict__ br,
    const unsigned int* __restrict__ cand_cnt,
    unsigned long long* __restrict__ cand_sb,
    double* __restrict__ cand_ry, double* __restrict__ cand_rx)
{
  __shared__ double xbuf[RC2][264];    // 33.8 KB
  __shared__ double redd[256];
  const int cnt = (int)*cand_cnt;
  const int c0 = blockIdx.x * RC2;
  if (c0 >= cnt) return;
  const int tid = threadIdx.x;

  double a2[4][RC2];
#pragma unroll
  for (int j = 0; j < 4; ++j)
#pragma unroll
    for (int c = 0; c < RC2; ++c) a2[j][c] = 0.0;

  for (int kc = 0; kc < 4; ++kc) {
    __syncthreads();
#pragma unroll
    for (int c = 0; c < RC2; ++c) {
      const int row = (c0 + c < cnt) ? c0 + c : c0;
      xbuf[c][tid] = x1g[(size_t)row * 1024 + (kc << 8) + tid];
    }
    __syncthreads();
    const float* wbase = &Wfc[(size_t)(kc << 8) * 1024 + (tid << 2)];
    float4 wf = *(const float4*)wbase;
    for (int kk = 0; kk < 256; ++kk) {
      const float4 wfn = (kk + 1 < 256)
          ? *(const float4*)(wbase + (size_t)(kk + 1) * 1024) : wf;
      double w[4];
      w[0] = (double)wf.x; w[1] = (double)wf.y;
      w[2] = (double)wf.z; w[3] = (double)wf.w;
#pragma unroll
      for (int c = 0; c < RC2; ++c) {
        const double xv = xbuf[c][kk];
#pragma unroll
        for (int j = 0; j < 4; ++j) a2[j][c] = fma(w[j], xv, a2[j][c]);
      }
      wf = wfn;
    }
  }

  const float4 bff = *(const float4*)&bfc[tid << 2];
  const float4 wsf = *(const float4*)&Wsc[tid << 2];
  const float4 wr01 = *(const float4*)&Wrg[(tid << 3)];
  const float4 wr23 = *(const float4*)&Wrg[(tid << 3) + 4];
  const double bfv[4] = {(double)bff.x, (double)bff.y, (double)bff.z, (double)bff.w};
  const double wsv[4] = {(double)wsf.x, (double)wsf.y, (double)wsf.z, (double)wsf.w};
  const double w0v[4] = {(double)wr01.x, (double)wr01.z, (double)wr23.x, (double)wr23.z};
  const double w1v[4] = {(double)wr01.y, (double)wr01.w, (double)wr23.y, (double)wr23.w};

  __syncthreads();
  for (int c = 0; c < RC2; ++c) {
    double s = 0.0, ry = 0.0, rx = 0.0;
#pragma unroll
    for (int j = 0; j < 4; ++j) {
      double v = a2[j][c] + bfv[j];
      v = v > 0.0 ? v : 0.0;
      s  = fma(v, wsv[j], s);
      ry = fma(v, w0v[j], ry);
      rx = fma(v, w1v[j], rx);
    }
    for (int h = 0; h < 3; ++h) {
      redd[tid] = (h == 0) ? s : (h == 1) ? ry : rx;
      __syncthreads();
      for (int st = 128; st > 0; st >>= 1) {
        if (tid < st) redd[tid] += redd[tid + st];
        __syncthreads();
      }
      if (tid == 0 && c0 + c < cnt) {
        const double tot = redd[0];
        if (h == 0) {
          const double lg = tot + (double)bs[0];
          const double sg = 1.0 / (1.0 + exp(-lg));
          cand_sb[c0 + c] = (unsigned long long)__double_as_longlong(sg);
        } else if (h == 1) cand_ry[c0 + c] = tot + (double)br[0];
        else               cand_rx[c0 + c] = tot + (double)br[1];
      }
      __syncthreads();
    }
  }
}

// ---------------------------------------------------------------------------
// proposal: f64 radix-select top-2000, DETERMINISTIC compaction (ascending
// slot = ascending cell), bitonic sort with (score desc, slot asc) tie-break,
// f64 NMS, emit.  Single block, 1024 threads.
// ---------------------------------------------------------------------------
__global__ __launch_bounds__(1024) void proposal_kernel(
    const unsigned int* __restrict__ cand_idx,
    const unsigned int* __restrict__ cand_cnt,
    const unsigned long long* __restrict__ cand_sb,
    const double* __restrict__ cand_ry, const double* __restrict__ cand_rx,
    unsigned int* __restrict__ cellrank, unsigned int* __restrict__ nbrg,
    double* __restrict__ cyg, double* __restrict__ cxg,
    int* __restrict__ startb, float* __restrict__ out_ps,
    float* __restrict__ out_dec)
{
  __shared__ unsigned long long sk[2048];
  __shared__ unsigned int si[2048];
  __shared__ unsigned int hist[256];
  __shared__ unsigned long long sh_pref;
  __shared__ unsigned char kept[2048];
  __shared__ unsigned char nbrc[2048];
  __shared__ int scan[2048];
  __shared__ volatile unsigned int changed;
  __shared__ int sh_maxreg;

  const int tid = threadIdx.x;
  const int cnt = (int)*cand_cnt;

  for (int i = tid; i < 65536; i += 1024) cellrank[i] = 0xFFFFFFFFu;

  // ---- radix-select the 2000th-largest f64-score bit pattern
  unsigned long long prefix = 0ull;
  int need = KTOP;
  for (int byte = 7; byte >= 0; --byte) {
    if (tid < 256) hist[tid] = 0u;
    __syncthreads();
    const int sh = byte * 8;
    const unsigned long long mhi =
        (byte == 7) ? 0ull : (0xFFFFFFFFFFFFFFFFull << (sh + 8));
    for (int i = tid; i < cnt; i += 1024) {
      const unsigned long long k = cand_sb[i];
      if ((k & mhi) == prefix) atomicAdd(&hist[(unsigned int)((k >> sh) & 255u)], 1u);
    }
    __syncthreads();
    if (tid == 0) {
      int cum = 0;
      for (int v = 255; v >= 0; --v) {
        const int c = (int)hist[v];
        if (cum + c >= need) {
          sh_pref = prefix | ((unsigned long long)(unsigned)v << sh);
          break;
        }
        cum += c;
      }
      hist[0] = (unsigned int)cum;
    }
    __syncthreads();
    prefix = sh_pref;
    need -= (int)hist[0];
    __syncthreads();
  }
  const unsigned long long T = prefix;

  // ---- deterministic compaction: thread t owns slots [4t, 4t+4)
  const int s0 = tid << 2;
  unsigned long long kv[4];
  int ca = 0, cb = 0;
#pragma unroll
  for (int q = 0; q < 4; ++q) {
    const int s = s0 + q;
    kv[q] = (s < cnt) ? cand_sb[s] : 0ull;
    if (s < cnt) { if (kv[q] > T) ++ca; else if (kv[q] == T) ++cb; }
  }
  scan[tid] = ca;
  __syncthreads();
  for (int off = 1; off < 1024; off <<= 1) {
    const int a = scan[tid];
    const int b = (tid >= off) ? scan[tid - off] : 0;
    __syncthreads();
    scan[tid] = a + b;
    __syncthreads();
  }
  int posA = scan[tid] - ca;         // exclusive
  const int atot = scan[1023];
  __syncthreads();
  scan[tid] = cb;
  __syncthreads();
  for (int off = 1; off < 1024; off <<= 1) {
    const int a = scan[tid];
    const int b = (tid >= off) ? scan[tid - off] : 0;
    __syncthreads();
    scan[tid] = a + b;
    __syncthreads();
  }
  int posB = atot + (scan[tid] - cb);
  __syncthreads();
#pragma unroll
  for (int q = 0; q < 4; ++q) {
    const int s = s0 + q;
    if (s < cnt) {
      if (kv[q] > T) {
        sk[posA] = kv[q]; si[posA] = (unsigned int)s; ++posA;
      } else if (kv[q] == T) {
        if (posB < KTOP) { sk[posB] = kv[q]; si[posB] = (unsigned int)s; }
        ++posB;
      }
    }
  }
  __syncthreads();
  for (int i = tid; i < 2048; i += 1024)
    if (i >= KTOP) { sk[i] = 0ull; si[i] = 0u; }
  if (tid == 0) sh_maxreg = 0;
  __syncthreads();

  // ---- bitonic sort 2048 descending by (score bits, then ascending slot)
  for (int k = 2; k <= 2048; k <<= 1) {
    for (int j = k >> 1; j > 0; j >>= 1) {
      const int i = (tid & (j - 1)) | ((tid & ~(j - 1)) << 1);
      const int ixj = i | j;
      const unsigned long long a = sk[i], b = sk[ixj];
      const unsigned int ia = si[i], ib = si[ixj];
      const bool up = ((i & k) == 0);
      const bool lt = (a < b) || (a == b && ia > ib);
      const bool gt = (a > b) || (a == b && ia < ib);
      if (up ? lt : gt) {
        sk[i] = b; sk[ixj] = a;
        si[i] = ib; si[ixj] = ia;
      }
      __syncthreads();
    }
  }

  // ---- decode top-2000 (f64)
  for (int r = tid; r < KTOP; r += 1024) {
    const unsigned int slot = si[r];
    const unsigned int idx = cand_idx[slot];
    const int row = (int)(idx >> 8), col = (int)(idx & 255u);
    const double ry = cand_ry[slot], rx = cand_rx[slot];
    cyg[r] = ((double)row + 0.5) + ry;
    cxg[r] = ((double)col + 0.5) + rx;
    kept[r] = 1; nbrc[r] = 0;
    cellrank[idx] = (unsigned int)r;
    atomicMax(&sh_maxreg, __float_as_int((float)fabs(ry)));
    atomicMax(&sh_maxreg, __float_as_int((float)fabs(rx)));
  }
  __syncthreads();
  const float maxreg = __int_as_float(sh_maxreg);
  int rad = (int)(1.0f + 2.0f * maxreg) + 1;
  if (rad > 8) rad = 8;
  if (rad < 1) rad = 1;

  // ---- earlier-close neighbor lists (f64 distances, no contraction)
  for (int r = tid; r < KTOP; r += 1024) {
    const unsigned int idx = cand_idx[si[r]];
    const int row = (int)(idx >> 8), col = (int)(idx & 255u);
    int n = 0;
    const double pyr = cyg[r], pxr = cxg[r];
    for (int dy = -rad; dy <= rad; ++dy) {
      const int yy = row + dy; if (yy < 0 || yy >= 256) continue;
      for (int dx = -rad; dx <= rad; ++dx) {
        if (dy == 0 && dx == 0) continue;
        const int xx = col + dx; if (xx < 0 || xx >= 256) continue;
        const unsigned int q = cellrank[yy * 256 + xx];
        if (q < (unsigned int)r) {
          const double t1 = __dsub_rn(pyr, cyg[q]);
          const double t2 = __dsub_rn(pxr, cxg[q]);
          const double d2 = __dadd_rn(__dmul_rn(t1, t1), __dmul_rn(t2, t2));
          if (d2 < 1.0) { if (n < 16) nbrg[(size_t)r * 16 + n] = q; ++n; }
        }
      }
    }
    nbrc[r] = (unsigned char)(n < 16 ? n : 16);
  }
  __syncthreads();

  // ---- fixpoint == sequential NMS (unique fixpoint on rank-DAG)
  for (int it = 0; it < 4096; ++it) {
    __syncthreads();
    if (tid == 0) changed = 0;
    __syncthreads();
    for (int r = tid; r < KTOP; r += 1024) {
      const int nc = nbrc[r];
      if (nc) {
        int kvv = 1;
        for (int t = 0; t < nc; ++t)
          if (kept[nbrg[(size_t)r * 16 + t]]) { kvv = 0; break; }
        if (kvv != (int)kept[r]) { kept[r] = (unsigned char)kvv; changed = 1; }
      }
    }
    __syncthreads();
    if (changed == 0) break;
  }

  // ---- inclusive prefix scan of kept
  scan[tid]        = (tid < KTOP) ? (int)kept[tid] : 0;
  scan[tid + 1024] = (tid + 1024 < KTOP) ? (int)kept[tid + 1024] : 0;
  __syncthreads();
  for (int off = 1; off < 2048; off <<= 1) {
    const int a0 = scan[tid];
    const int b0 = (tid >= off) ? scan[tid - off] : 0;
    const int a1 = scan[tid + 1024];
    const int b1 = (tid + 1024 >= off) ? scan[tid + 1024 - off] : 0;
    __syncthreads();
    scan[tid] = a0 + b0;
    scan[tid + 1024] = a1 + b1;
    __syncthreads();
  }
  const int total = scan[KTOP - 1];

  // ---- emit
  for (int r = tid; r < KTOP; r += 1024) {
    int slot = -1;
    if (kept[r]) { const int p = scan[r] - 1; if (p < MAXOUT) slot = p; }
    else { const int p = total + (r - scan[r]); if (p < MAXOUT) slot = p; }
    if (slot >= 0) {
      const double sg = __longlong_as_double((long long)sk[r]);
      out_ps[slot] = kept[r] ? (float)sg : -1.0f;
      const double py = cyg[r], px = cxg[r];
      out_dec[slot * 2]     = (float)(py * 4.0);
      out_dec[slot * 2 + 1] = (float)(px * 4.0);
      int sy = (int)rint(py * 2.0 - 24.0);
      int sx = (int)rint(px * 2.0 - 24.0);
      sy = sy < 0 ? 0 : (sy > 464 ? 464 : sy);
      sx = sx < 0 ? 0 : (sx > 464 ? 464 : sx);
      startb[slot * 2] = sy; startb[slot * 2 + 1] = sx;
    }
  }
}

// ---------------------------------------------------------------------------
// conv_i via bf16 MFMA: 3x3 32->64 + relu on 48x48 crops -> h (bf16).
// ---------------------------------------------------------------------------
#define ISTR 40   // input pixel stride in bf16 elems (80 B)
__global__ __launch_bounds__(256) void conv_i_mfma(
    const float* __restrict__ seg, const unsigned short* __restrict__ WiB,
    const float* __restrict__ bi, const int* __restrict__ startb,
    unsigned short* __restrict__ h, int inst0)
{
  __shared__ __align__(16) unsigned short ins[500 * ISTR];   // 40 KB (reused)
  const int li = blockIdx.y;
  const int inst = inst0 + li;
  const int tile = blockIdx.x;              // 0..5
  const int r0 = tile << 3;
  const int tid = threadIdx.x;
  const int sy = startb[inst * 2], sx = startb[inst * 2 + 1];

  for (int p = tid; p < 500; p += 256) {
    const int rr = p / 50, cc2 = p - rr * 50;
    const int ir = r0 - 1 + rr, ic = cc2 - 1;
    unsigned short* dst = &ins[p * ISTR];
    if (ir >= 0 && ir < 48 && ic >= 0 && ic < 48) {
      const float* src = &seg[((size_t)(sy + ir) * 512 + (sx + ic)) * 32];
#pragma unroll
      for (int q = 0; q < 8; ++q) {
        const float4 v = *(const float4*)&src[q << 2];
        const unsigned int lo = (unsigned int)f2bf(v.x) | ((unsigned int)f2bf(v.y) << 16);
        const unsigned int hi = (unsigned int)f2bf(v.z) | ((unsigned int)f2bf(v.w) << 16);
        *(uint2*)&dst[q << 2] = make_uint2(lo, hi);
      }
    } else {
#pragma unroll
      for (int q = 0; q < 4; ++q) *(uint4*)&dst[q << 3] = make_uint4(0, 0, 0, 0);
    }
  }
  __syncthreads();

  const int wv = tid >> 6, lane = tid & 63;
  const int l15 = lane & 15, quad = lane >> 4;
  const int wmb = wv * 96;

  int pbase[6];
#pragma unroll
  for (int i = 0; i < 6; ++i) {
    const int m = wmb + (i << 4) + l15;
    pbase[i] = (m / 48 + 1) * 50 + (m % 48) + 1;
  }

  f32x4 acc[6][4];
  const f32x4 z4 = {0.f, 0.f, 0.f, 0.f};
#pragma unroll
  for (int i = 0; i < 6; ++i)
#pragma unroll
    for (int j = 0; j < 4; ++j) acc[i][j] = z4;

  for (int tap = 0; tap < 9; ++tap) {
    const int off = (tap / 3 - 1) * 50 + (tap % 3 - 1);
    short8 b[4];
#pragma unroll
    for (int j = 0; j < 4; ++j)
      b[j] = *(const short8*)&WiB[((tap << 6) + (j << 4) + l15) * 32 + (quad << 3)];
#pragma unroll
    for (int i = 0; i < 6; ++i) {
      const short8 a = *(const short8*)&ins[(pbase[i] + off) * ISTR + (quad << 3)];
#pragma unroll
      for (int j = 0; j < 4; ++j)
        acc[i][j] = __builtin_amdgcn_mfma_f32_16x16x32_bf16(a, b[j], acc[i][j], 0, 0, 0);
    }
  }

  float bv[4];
#pragma unroll
  for (int j = 0; j < 4; ++j) bv[j] = bi[(j << 4) + l15];

  for (int half = 0; half < 2; ++half) {
    __syncthreads();
    if ((wv >> 1) == half) {
#pragma unroll
      for (int i = 0; i < 6; ++i)
#pragma unroll
        for (int j = 0; j < 4; ++j)
#pragma unroll
          for (int rg = 0; rg < 4; ++rg) {
            const int m = wmb + (i << 4) + (quad << 2) + rg;
            const int pp = m - half * 192;
            const float v = fmaxf(acc[i][j][rg] + bv[j], 0.f);
            ins[pp * 72 + (j << 4) + l15] = f2bf(v);
          }
    }
    __syncthreads();
    for (int t = tid; t < 192 * 8; t += 256) {
      const int pp = t >> 3, c8 = t & 7;
      const uint4 v = *(const uint4*)&ins[pp * 72 + (c8 << 3)];
      *(uint4*)&h[((size_t)li * 2304 + (tile * 384 + half * 192 + pp)) * 64 + (c8 << 3)] = v;
    }
  }
}

// ---------------------------------------------------------------------------
// conv_o: 3x3, 64->1 + sigmoid on bf16 h; emits instance_coords.
// ---------------------------------------------------------------------------
__global__ __launch_bounds__(256) void conv_o_kernel(
    const unsigned short* __restrict__ h, const float* __restrict__ Wo,
    const float* __restrict__ bo, const int* __restrict__ startb,
    float* __restrict__ out_io, float* __restrict__ out_ic, int inst0)
{
  __shared__ __align__(16) unsigned short hs[324 * 72];   // 46.7 KB
  __shared__ float wos[576];
  const int li = blockIdx.y;
  const int inst = inst0 + li;
  const int tile = blockIdx.x;
  const int ty0 = (tile / 3) << 4;
  const int tx0 = (tile % 3) << 4;
  const int tid = threadIdx.x;

  for (int i = tid; i < 576; i += 256) wos[i] = Wo[i];
  for (int p = tid; p < 324; p += 256) {
    const int iy = p / 18, ix = p - iy * 18;
    const int gy = ty0 - 1 + iy, gx = tx0 - 1 + ix;
    unsigned short* dst = &hs[p * 72];
    if (gy >= 0 && gy < 48 && gx >= 0 && gx < 48) {
      const unsigned short* src = &h[((size_t)li * 2304 + gy * 48 + gx) * 64];
#pragma unroll
      for (int q = 0; q < 8; ++q) *(uint4*)&dst[q << 3] = *(const uint4*)&src[q << 3];
    } else {
#pragma unroll
      for (int q = 0; q < 8; ++q) *(uint4*)&dst[q << 3] = make_uint4(0, 0, 0, 0);
    }
  }
  __syncthreads();

  const int ly = tid >> 4, lx = tid & 15;
  float a = 0.f;
#pragma unroll
  for (int ky = 0; ky < 3; ++ky)
#pragma unroll
    for (int kx = 0; kx < 3; ++kx) {
      const unsigned short* hp = &hs[((ly + ky) * 18 + lx + kx) * 72];
      const float* wp = &wos[(ky * 3 + kx) << 6];
#pragma unroll
      for (int c8 = 0; c8 < 8; ++c8) {
        const uint4 hv = *(const uint4*)&hp[c8 << 3];
        const unsigned int uu[4] = {hv.x, hv.y, hv.z, hv.w};
#pragma unroll
        for (int e = 0; e < 4; ++e) {
          const float f0 = __uint_as_float(uu[e] << 16);
          const float f1 = __uint_as_float(uu[e] & 0xFFFF0000u);
          a = fmaf(f0, wp[(c8 << 3) + (e << 1)], a);
          a = fmaf(f1, wp[(c8 << 3) + (e << 1) + 1], a);
        }
      }
    }
  a += bo[0];
  const float o = 1.f / (1.f + expf(-a));
  const int gy = ty0 + ly, gx = tx0 + lx;
  const size_t p = ((size_t)inst * 48 + gy) * 48 + gx;
  out_io[p] = o;
  const int sy = startb[inst * 2], sx = startb[inst * 2 + 1];
  out_ic[p * 2]     = (float)(sy + gy);
  out_ic[p * 2 + 1] = (float)(sx + gx);
}

// ---------------------------------------------------------------------------
extern "C" void kernel_launch(void* const* d_in, const int* in_sizes, int n_in,
                              void* d_out, int out_size, void* d_ws, size_t ws_size,
                              hipStream_t stream)
{
  const float* df  = (const float*)d_in[0];
  const float* seg = (const float*)d_in[1];
  const float* Wc  = (const float*)d_in[2];
  const float* bc  = (const float*)d_in[3];
  const float* Wfc = (const float*)d_in[4];
  const float* bfc = (const float*)d_in[5];
  const float* Wsc = (const float*)d_in[6];
  const float* bs  = (const float*)d_in[7];
  const float* Wrg = (const float*)d_in[8];
  const float* br  = (const float*)d_in[9];
  const float* Wi  = (const float*)d_in[10];
  const float* bi  = (const float*)d_in[11];
  const float* Wo  = (const float*)d_in[12];
  const float* bo  = (const float*)d_in[13];

  const size_t SZ_WCT = 2359296ull, SZ_WFT = 2097152ull, SZ_WIB = 36864ull,
               SZ_PART = 2097152ull, SZ_SC = 262144ull, SZ_CR = 262144ull,
               SZ_NB = 131072ull, SZ_STB = 4096ull, SZ_CI = CANDCAP * 4ull,
               SZ_SB = CANDCAP * 8ull, SZ_RY = CANDCAP * 8ull,
               SZ_RX = CANDCAP * 8ull, SZ_CY = 16384ull, SZ_CX = 16384ull,
               SZ_X1G = (size_t)CANDCAP * 1024ull * 8ull,   // 33.5 MB, own slot
               SZ_CNT = 256ull;
  const size_t FIXED = SZ_WCT + SZ_WFT + SZ_WIB + SZ_PART + SZ_SC + SZ_CR +
                       SZ_NB + SZ_STB + SZ_CI + SZ_SB + SZ_RY + SZ_RX +
                       SZ_CY + SZ_CX + SZ_X1G + SZ_CNT;
  char* w = (char*)d_ws;
  size_t region = (ws_size > FIXED) ? ((ws_size - FIXED) & ~(size_t)255) : 0;
  char* fb = w + region;
  unsigned short* WcT = (unsigned short*)fb;   fb += SZ_WCT;
  unsigned short* WfcT = (unsigned short*)fb;  fb += SZ_WFT;
  unsigned short* WiB = (unsigned short*)fb;   fb += SZ_WIB;
  float* part = (float*)fb;                    fb += SZ_PART;
  float* scores = (float*)fb;                  fb += SZ_SC;
  unsigned int* cellrank = (unsigned int*)fb;  fb += SZ_CR;
  unsigned int* nbrg = (unsigned int*)fb;      fb += SZ_NB;
  int* startb = (int*)fb;                      fb += SZ_STB;
  unsigned int* cand_idx = (unsigned int*)fb;  fb += SZ_CI;
  unsigned long long* cand_sb = (unsigned long long*)fb; fb += SZ_SB;
  double* cand_ry = (double*)fb;               fb += SZ_RY;
  double* cand_rx = (double*)fb;               fb += SZ_RX;
  double* cyg = (double*)fb;                   fb += SZ_CY;
  double* cxg = (double*)fb;                   fb += SZ_CX;
  double* x1g = (double*)fb;                   fb += SZ_X1G;
  unsigned int* cand_cnt = (unsigned int*)fb;
  unsigned short* x1b = (unsigned short*)w;    // big region: bf16 x1 chunk
  unsigned short* hb = (unsigned short*)w;     // big region: bf16 inst crops

  size_t tiles_fit = region / 131072ull;
  int pt_chunk = 2;
  while ((size_t)(pt_chunk * 2) <= tiles_fit && pt_chunk < 1024) pt_chunk <<= 1;
  size_t inst_fit = region / 294912ull;        // 48*48*64*2B per instance
  const int opts[12] = {500, 250, 125, 100, 50, 25, 20, 10, 5, 4, 2, 1};
  int inst_chunk = 1;
  for (int o = 0; o < 12; ++o)
    if ((size_t)opts[o] <= inst_fit) { inst_chunk = opts[o]; break; }

  float* out = (float*)d_out;
  float* out_ps  = out;
  float* out_dec = out + 500;
  float* out_io  = out + 1500;
  float* out_ic  = out + 1153500;

  transpose_bf16_kernel<<<dim3(36, 32), 256, 0, stream>>>(Wc, WcT, 1152, 1024);
  transpose_bf16_kernel<<<dim3(32, 32), 256, 0, stream>>>(Wfc, WfcT, 1024, 1024);
  prep_wib_kernel<<<72, 256, 0, stream>>>(Wi, WiB);

  for (int c = 0; c < 1024 / pt_chunk; ++c) {
    conv1_mfma<<<dim3(8, pt_chunk / 2), 256, 0, stream>>>(df, WcT, bc, x1b,
                                                          c * pt_chunk);
    fc_mfma<<<dim3(8, pt_chunk / 2), 256, 0, stream>>>(x1b, WfcT, bfc, Wsc,
                                                       part, c * pt_chunk);
  }
  head_finalize_kernel<<<256, 256, 0, stream>>>(part, bs, scores);
  select_kernel<<<1, 1024, 0, stream>>>(scores, cand_idx, cand_cnt);
  rescore_conv<<<CANDCAP / RC2, 256, 0, stream>>>(df, Wc, bc, cand_idx,
                                                  cand_cnt, x1g);
  rescore_fc<<<CANDCAP / RC2, 256, 0, stream>>>(x1g, Wfc, bfc, Wsc, bs, Wrg,
                                                br, cand_cnt, cand_sb,
                                                cand_ry, cand_rx);
  proposal_kernel<<<1, 1024, 0, stream>>>(cand_idx, cand_cnt, cand_sb, cand_ry,
                                          cand_rx, cellrank, nbrg, cyg, cxg,
                                          startb, out_ps, out_dec);
  for (int c = 0; c < 500 / inst_chunk; ++c) {
    conv_i_mfma<<<dim3(6, inst_chunk), 256, 0, stream>>>(seg, WiB, bi, startb,
                                                         hb, c * inst_chunk);
    conv_o_kernel<<<dim3(9, inst_chunk), 256, 0, stream>>>(hb, Wo, bo, startb,
                                                           out_io, out_ic,
                                                           c * inst_chunk);
  }
}